// Round 7
// baseline (165.872 us; speedup 1.0000x reference)
//
#include <hip/hip_runtime.h>

// Criterion_BiNet — adjoint multi-scale dice, u8 fixed-point pipeline.
// inter = p · (A^4 t); sum_p = p · (A^2 1); sum_t = t · (A^2 1).
// K1 hpool_mono: per (g,bd,wtile): load raw once, H-axis box^4 for ALL 5
//    scales in regs (shuffle halos), store u8 q=RNE(255x); + mono blocks.
// K2 wd_dot0: scale blocks (one (s,g,b,h) each): W-box^4 (shuffle, u8 decode
//    folded into pass 0) + D-box^4+dot fused (KD>1) or float4 dot (KD=1);
//    plus dot0/wsum streaming blocks (LDS overlaid in SH union).
// K3 fin_pre + K4 finalize.
// Slots: [0..35] inter (pair*6+s), [36..71] sum_p, [72..89] sum_t, [90] mono.

#define DIMB 4
#define DIMD 28
#define DIMH 160
#define DIMW 160
#define HW   (DIMH * DIMW)
#define DHW  (DIMD * HW)
#define VOL_N (DIMB * DHW)      // 2,867,200
#define PGRID 640
#define NSLOTS 91
#define DICE_EPS 1e-7

__device__ __forceinline__ float u2f(int pos, int k, int L) {
    if (k == 1) return 1.f;
    int r = k >> 1;
    float s = 0.f;
    for (int j = max(pos - r, 0); j <= min(pos + r, L - 1); ++j)
        s += (float)(min(j + r, L - 1) - max(j - r, 0) + 1);
    return s / (float)(k * k);
}

__device__ __forceinline__ float wave_sum(float v) {
#pragma unroll
    for (int o = 1; o < 64; o <<= 1) v += __shfl_xor(v, o, 64);
    return v;
}

template<int K>
__device__ __forceinline__ void box4_col(float (&x)[28]) {
    constexpr int R = K / 2;
    constexpr float INVK = 1.f / (float)K;
#pragma unroll
    for (int p = 0; p < 4; ++p) {
        float y[28];
        float s = 0.f;
#pragma unroll
        for (int j = 0; j <= R; ++j) s += x[j];
        y[0] = s;
#pragma unroll
        for (int i = 1; i < 28; ++i) {
            if (i + R < 28) s += x[i + R];
            if (i - R - 1 >= 0) s -= x[i - R - 1];
            y[i] = s;
        }
#pragma unroll
        for (int i = 0; i < 28; ++i) x[i] = y[i] * INVK;
    }
}

// ---------------- K1: H-axis box^4 (all 5 scales from one raw load) --------
template<int K>
__device__ __forceinline__ void hstore(const float (&raw)[40],
                                       unsigned char* __restrict__ ob,
                                       int l, int c, int wl, int h0)
{
    constexpr int R = K / 2;
    constexpr float INVK = 1.f / (float)K;
    float ox[40];
#pragma unroll
    for (int i = 0; i < 40; ++i) ox[i] = raw[i];
#pragma unroll
    for (int pass = 0; pass < 4; ++pass) {
        float lo[R], hi[R];
#pragma unroll
        for (int i = 0; i < R; ++i) {
            float a = __shfl(ox[40 - R + i], l - 16, 64);
            lo[i] = (c == 0) ? 0.f : a;
            float b = __shfl(ox[i], l + 16, 64);
            hi[i] = (c == 3) ? 0.f : b;
        }
#define HWIN(j) ((j) < R ? lo[(j)] : ((j) < R + 40 ? ox[(j) - R] : hi[(j) - R - 40]))
        float out[40];
        float s = 0.f;
#pragma unroll
        for (int j = 0; j <= 2 * R; ++j) s += HWIN(j);
        out[0] = s * INVK;
#pragma unroll
        for (int i = 1; i < 40; ++i) {
            s += HWIN(i + 2 * R) - HWIN(i - 1);
            out[i] = s * INVK;
        }
#undef HWIN
#pragma unroll
        for (int i = 0; i < 40; ++i) ox[i] = out[i];
    }
#pragma unroll
    for (int i = 0; i < 40; ++i)
        ob[(h0 + i) * DIMW + wl] = (unsigned char)__float2uint_rn(ox[i] * 255.f);
}

__global__ __launch_bounds__(256) void hpool_mono(const float* __restrict__ g0,
    const float* __restrict__ g1, const float* __restrict__ g2,
    const float* __restrict__ o6, unsigned char* __restrict__ bufs,
    double* __restrict__ partials)
{
    __shared__ float redSm[4];
    int bx = blockIdx.x;
    if (bx < 840) {
        int u = bx * 2 + (threadIdx.x >> 7);   // 1680 units = 3g * 112bd * 5wt
        int tt = threadIdx.x & 127;
        int g = u / 560, r = u - g * 560;
        int bd = r / 5, wt = r - bd * 5;
        const float* in = (g == 0) ? g0 : (g == 1) ? g1 : g2;
        int l = tt & 63, v = tt >> 6;
        int c = l >> 4, wl = v * 16 + (l & 15), h0 = c * 40;
        const float* base = in + (size_t)bd * HW + wt * 32;
        float raw[40];
#pragma unroll
        for (int i = 0; i < 40; ++i) raw[i] = base[(h0 + i) * DIMW + wl];
        unsigned char* ob = bufs + (size_t)g * 5 * VOL_N + (size_t)bd * HW + wt * 32;
        hstore<5> (raw, ob + 0 * (size_t)VOL_N, l, c, wl, h0);
        hstore<13>(raw, ob + 1 * (size_t)VOL_N, l, c, wl, h0);
        hstore<23>(raw, ob + 2 * (size_t)VOL_N, l, c, wl, h0);
        hstore<31>(raw, ob + 3 * (size_t)VOL_N, l, c, wl, h0);
        hstore<41>(raw, ob + 4 * (size_t)VOL_N, l, c, wl, h0);
    } else {
        int mb = bx - 840;
        const int N4 = VOL_N / 4, PB = N4 / DIMB;
        float acc = 0.f;
        const float4* p = (const float4*)o6;
        for (int i = mb * 256 + threadIdx.x; i < N4; i += PGRID * 256) {
            int b = i / PB, r4 = i - b * PB;
            size_t a = (size_t)(b * 6) * PB + r4;
            float4 prev = p[a];
#pragma unroll
            for (int cc = 1; cc < 6; ++cc) {
                float4 cur = p[a + (size_t)cc * PB];
                acc += fmaxf(prev.x - cur.x, 0.f) + fmaxf(prev.y - cur.y, 0.f)
                     + fmaxf(prev.z - cur.z, 0.f) + fmaxf(prev.w - cur.w, 0.f);
                prev = cur;
            }
        }
        float rv = wave_sum(acc * 2.f);
        int lane = threadIdx.x & 63, wid = threadIdx.x >> 6;
        if (lane == 0) redSm[wid] = rv;
        __syncthreads();
        if (threadIdx.x == 0)
            partials[(size_t)90 * PGRID + mb] =
                (double)redSm[0] + redSm[1] + redSm[2] + redSm[3];
    }
}

// ---------------- K2: W-box^4 + D-box^4 + dots ----------------
template<int K, int KD>
__device__ __forceinline__ void wd_scale(const unsigned char* __restrict__ tb,
    const float* __restrict__ pc, const float* __restrict__ pp,
    float* SH, int t, size_t base0, double* __restrict__ partials,
    int slot_c, int slot_p, int bh)
{
    constexpr int R = K / 2;
    float (*S)[164] = (float(*)[164])SH;
    int l = t & 63, wid = t >> 6;
    int rr = wid * 7 + (l >> 3), c = l & 7;
    bool act = (l < 56);
    float ox[20];
#pragma unroll
    for (int i = 0; i < 20; ++i) ox[i] = 0.f;
    if (act) {
        const unsigned char* hp = tb + base0 + (size_t)rr * HW + c * 20;
        unsigned int u[5];
#pragma unroll
        for (int q = 0; q < 5; ++q) u[q] = *(const unsigned int*)(hp + 4 * q);
#pragma unroll
        for (int q = 0; q < 5; ++q) {
#pragma unroll
            for (int j = 0; j < 4; ++j)
                ox[4 * q + j] = (float)((u[q] >> (8 * j)) & 0xFFu);
        }
    }
#pragma unroll
    for (int pass = 0; pass < 4; ++pass) {
        const float scl = (pass == 0) ? (1.f / ((float)K * 255.f)) : (1.f / (float)K);
        float lo[R], hi[R];
#pragma unroll
        for (int i = 0; i < R; ++i) {
            float a = __shfl(ox[20 - R + i], l - 1, 64);
            lo[i] = (c == 0) ? 0.f : a;
            float b = __shfl(ox[i], l + 1, 64);
            hi[i] = (c == 7) ? 0.f : b;
        }
#define WWIN(j) ((j) < R ? lo[(j)] : ((j) < R + 20 ? ox[(j) - R] : hi[(j) - R - 20]))
        float out[20];
        float s = 0.f;
#pragma unroll
        for (int j = 0; j <= 2 * R; ++j) s += WWIN(j);
        out[0] = s * scl;
#pragma unroll
        for (int i = 1; i < 20; ++i) {
            s += WWIN(i + 2 * R) - WWIN(i - 1);
            out[i] = s * scl;
        }
#undef WWIN
#pragma unroll
        for (int i = 0; i < 20; ++i) ox[i] = out[i];
    }
    if (act) {
#pragma unroll
        for (int i = 0; i < 20; ++i) S[rr][c * 20 + i] = ox[i];
    }
    __syncthreads();
    float aic = 0.f, aip = 0.f;
    if constexpr (KD > 1) {
        if (t < DIMW) {
            float col[28];
#pragma unroll
            for (int j = 0; j < 28; ++j) col[j] = S[j][t];
            box4_col<KD>(col);
#pragma unroll
            for (int j = 0; j < 28; ++j) {
                size_t gi = base0 + (size_t)j * HW + t;
                aic += pc[gi] * col[j];
                aip += pp[gi] * col[j];
            }
        }
    } else {
        for (int e4 = t; e4 < 1120; e4 += 256) {      // FIXED: full 28 rows
            int dd = e4 / 40, w4 = e4 - dd * 40;
            size_t gb = base0 + (size_t)dd * HW + 4 * w4;
            float4 vc = *(const float4*)(pc + gb);
            float4 vp = *(const float4*)(pp + gb);
            float t0 = S[dd][4*w4], t1 = S[dd][4*w4+1];
            float t2 = S[dd][4*w4+2], t3 = S[dd][4*w4+3];
            aic += vc.x*t0 + vc.y*t1 + vc.z*t2 + vc.w*t3;
            aip += vp.x*t0 + vp.y*t1 + vp.z*t2 + vp.w*t3;
        }
    }
    float r1 = wave_sum(aic), r2 = wave_sum(aip);
    float* red2 = SH + 28 * 164;
    if (l == 0) { red2[wid * 2] = r1; red2[wid * 2 + 1] = r2; }
    __syncthreads();
    if (t < 2) {
        double rv = (double)red2[t] + red2[2 + t] + red2[4 + t] + red2[6 + t];
        partials[(size_t)(t == 0 ? slot_c : slot_p) * PGRID + bh] = rv;
    }
}

__global__ __launch_bounds__(256) void wd_dot0(const unsigned char* __restrict__ bufs,
    const float* __restrict__ pc0, const float* __restrict__ pp0,
    const float* __restrict__ pc1, const float* __restrict__ pp1,
    const float* __restrict__ pc2, const float* __restrict__ pp2,
    const float* __restrict__ tr0, const float* __restrict__ tr1,
    const float* __restrict__ tr2, double* __restrict__ partials)
{
    __shared__ float SH[28 * 164 + 8];     // scale: S+red2 | dot0: cD/cL/redS
    int bx = blockIdx.x;
    int t = threadIdx.x;
    if (bx < 9600) {
        int q = bx / 1920, r = bx - q * 1920;
        int s = 5 - q;                      // k41 blocks first
        int g = r / PGRID, bh = r - g * PGRID;
        int b = bh / DIMH, h = bh - b * DIMH;
        size_t base0 = (size_t)b * DHW + (size_t)h * DIMW;
        const float* pc = (g == 0) ? pc0 : (g == 1) ? pc1 : pc2;
        const float* pp = (g == 0) ? pp0 : (g == 1) ? pp1 : pp2;
        const unsigned char* tb = bufs + (size_t)(g * 5 + (s - 1)) * VOL_N;
        int slot_c = (2 * g) * 6 + s, slot_p = (2 * g + 1) * 6 + s;
        switch (s) {
            case 5: wd_scale<41, 9>(tb, pc, pp, SH, t, base0, partials, slot_c, slot_p, bh); break;
            case 4: wd_scale<31, 7>(tb, pc, pp, SH, t, base0, partials, slot_c, slot_p, bh); break;
            case 3: wd_scale<23, 5>(tb, pc, pp, SH, t, base0, partials, slot_c, slot_p, bh); break;
            case 2: wd_scale<13, 3>(tb, pc, pp, SH, t, base0, partials, slot_c, slot_p, bh); break;
            default: wd_scale<5, 1>(tb, pc, pp, SH, t, base0, partials, slot_c, slot_p, bh); break;
        }
    } else {
        int db = bx - 9600;                 // 1920 = 3g * 640
        int g = db / PGRID, blk = db - g * PGRID;
        const float* pc = (g == 0) ? pc0 : (g == 1) ? pc1 : pc2;
        const float* pp = (g == 0) ? pp0 : (g == 1) ? pp1 : pp2;
        const float* tr = (g == 0) ? tr0 : (g == 1) ? tr1 : tr2;
        float* cD = SH;                     // [6][28]
        float* cL = SH + 168;               // [6][160]
        float* redS = SH + 1128;            // [4][20]
        const int KDa[6] = {1, 1, 3, 5, 7, 9};
        const int KHa[6] = {1, 5, 13, 23, 31, 41};
        for (int e = t; e < 168; e += 256)
            cD[e] = u2f(e % 28, KDa[e / 28], DIMD);
        for (int e = t; e < 960; e += 256)
            cL[168 - 168 + 168 + e - e + e] = cL[e] = u2f(e % 160, KHa[e / 160], DIMH);
        __syncthreads();
        float aI0c = 0.f, aI0p = 0.f;
        float aS[18];
#pragma unroll
        for (int i = 0; i < 18; ++i) aS[i] = 0.f;
        const float4* c4p = (const float4*)pc;
        const float4* p4p = (const float4*)pp;
        const float4* t4p = (const float4*)tr;
        const int N4 = VOL_N / 4;
        for (int i4 = blk * 256 + t; i4 < N4; i4 += PGRID * 256) {
            int w4 = i4 % 40;
            int rest = i4 / 40;
            int h = rest % DIMH;
            int d = (rest / DIMH) % DIMD;
            float4 vc = c4p[i4], vp = p4p[i4], vt = t4p[i4];
            aI0c += vc.x*vt.x + vc.y*vt.y + vc.z*vt.z + vc.w*vt.w;
            aI0p += vp.x*vt.x + vp.y*vt.y + vp.z*vt.z + vp.w*vt.w;
#pragma unroll
            for (int s = 0; s < 6; ++s) {
                float cdh = cD[s * 28 + d] * cL[s * 160 + h];
                float w0 = cdh * cL[s * 160 + 4 * w4 + 0];
                float w1 = cdh * cL[s * 160 + 4 * w4 + 1];
                float w2 = cdh * cL[s * 160 + 4 * w4 + 2];
                float w3 = cdh * cL[s * 160 + 4 * w4 + 3];
                aS[s]      += w0*vc.x + w1*vc.y + w2*vc.z + w3*vc.w;
                aS[6 + s]  += w0*vp.x + w1*vp.y + w2*vp.z + w3*vp.w;
                aS[12 + s] += w0*vt.x + w1*vt.y + w2*vt.z + w3*vt.w;
            }
        }
        float vals[20];
        vals[0] = aI0c; vals[1] = aI0p;
#pragma unroll
        for (int i = 0; i < 18; ++i) vals[2 + i] = aS[i];
        int lane = t & 63, wid = t >> 6;
#pragma unroll
        for (int i = 0; i < 20; ++i) {
            float rv = wave_sum(vals[i]);
            if (lane == 0) redS[wid * 20 + i] = rv;
        }
        __syncthreads();
        if (t < 20) {
            double rv = (double)redS[t] + redS[20 + t] + redS[40 + t] + redS[60 + t];
            int slot;
            if (t == 0) slot = (2 * g) * 6;
            else if (t == 1) slot = (2 * g + 1) * 6;
            else {
                int i = t - 2, vv = i / 6, s = i % 6;
                slot = (vv == 0) ? 36 + (2 * g) * 6 + s
                     : (vv == 1) ? 36 + (2 * g + 1) * 6 + s
                                 : 72 + g * 6 + s;
            }
            partials[(size_t)slot * PGRID + blk] = rv;
        }
    }
}

// ---------------- K3/K4: reduction tail ----------------
__global__ __launch_bounds__(64) void fin_pre(const double* __restrict__ partials,
                                              double* __restrict__ ssum)
{
    int slot = blockIdx.x, t = threadIdx.x;
    double a = 0.0;
    for (int i = t; i < PGRID; i += 64) a += partials[(size_t)slot * PGRID + i];
#pragma unroll
    for (int o = 1; o < 64; o <<= 1) a += __shfl_xor(a, o, 64);
    if (t == 0) ssum[slot] = a;
}

__global__ void finalize(const double* __restrict__ ssum,
                         const float* __restrict__ off_a,
                         const float* __restrict__ off_b,
                         const float* __restrict__ off_ta,
                         const float* __restrict__ off_tb,
                         float* __restrict__ out)
{
    if (threadIdx.x == 0) {
        double loss = 0.0;
        for (int pair = 0; pair < 6; ++pair) {
            for (int s = 0; s < 6; ++s) {
                double inter = ssum[pair * 6 + s];
                double sp = ssum[36 + pair * 6 + s];
                double st = ssum[72 + (pair / 2) * 6 + s];
                loss += 0.2 * (1.0 - 2.0 * inter / (sp + st + DICE_EPS)) / 6.0;
            }
        }
        loss += 0.1 * (ssum[90] / (double)VOL_N);
        double oa = 0.0, ob = 0.0;
        for (int i = 0; i < 12; ++i) {
            oa += fabs((double)off_a[i] - (double)off_ta[i]);
            ob += fabs((double)off_b[i] - (double)off_tb[i]);
        }
        loss += 0.1 * (oa / 12.0) + 0.1 * (ob / 12.0);
        out[0] = (float)loss;
    }
}

extern "C" void kernel_launch(void* const* d_in, const int* in_sizes, int n_in,
                              void* d_out, int out_size, void* d_ws, size_t ws_size,
                              hipStream_t stream)
{
    double* partials = (double*)d_ws;                   // 91*640*8 = 465,920 B
    double* ssum = partials + (size_t)NSLOTS * PGRID;   // +91*8, < 512 KB
    unsigned char* bufs = (unsigned char*)d_ws + 512 * 1024;  // 15*VOL_N u8 = 43 MB

    const float* pred[6] = {(const float*)d_in[0], (const float*)d_in[1],
                            (const float*)d_in[3], (const float*)d_in[4],
                            (const float*)d_in[6], (const float*)d_in[7]};
    const float* gt[3] = {(const float*)d_in[2], (const float*)d_in[5],
                          (const float*)d_in[8]};

    hpool_mono<<<1480, 256, 0, stream>>>(gt[0], gt[1], gt[2],
                                         (const float*)d_in[9], bufs, partials);
    wd_dot0<<<11520, 256, 0, stream>>>(bufs, pred[0], pred[1], pred[2], pred[3],
                                       pred[4], pred[5], gt[0], gt[1], gt[2],
                                       partials);
    fin_pre<<<NSLOTS, 64, 0, stream>>>(partials, ssum);
    finalize<<<1, 64, 0, stream>>>(ssum,
                                   (const float*)d_in[10], (const float*)d_in[11],
                                   (const float*)d_in[12], (const float*)d_in[13],
                                   (float*)d_out);
}